// Round 1
// baseline (1610.294 us; speedup 1.0000x reference)
//
#include <hip/hip_runtime.h>
#include <hip/hip_bf16.h>
#include <stdint.h>

#define DIM 512
#define MLP 2048
#define NJ  24

typedef __attribute__((ext_vector_type(8))) short bf16x8;
typedef __attribute__((ext_vector_type(4))) float f32x4;

__device__ __forceinline__ void gload_lds16(const void* g, void* l) {
  __builtin_amdgcn_global_load_lds(
      (const __attribute__((address_space(1))) uint8_t*)g,
      (__attribute__((address_space(3))) uint8_t*)l, 16, 0, 0);
}

// ---------------- LayerNorm -> bf16 ----------------
// one wave per row of 512; block=256 -> 4 rows/block
__global__ void k_ln(const float* __restrict__ x, const float* __restrict__ lg,
                     const float* __restrict__ lb, __hip_bfloat16* __restrict__ xn,
                     int nrows) {
  const int row = blockIdx.x * 4 + (threadIdx.x >> 6);
  const int lane = threadIdx.x & 63;
  if (row >= nrows) return;
  const float* xr = x + (size_t)row * DIM + lane * 8;
  float v[8];
  *(float4*)(v)     = *(const float4*)(xr);
  *(float4*)(v + 4) = *(const float4*)(xr + 4);
  float s = 0.f, q = 0.f;
#pragma unroll
  for (int i = 0; i < 8; ++i) { s += v[i]; q += v[i] * v[i]; }
#pragma unroll
  for (int d = 1; d < 64; d <<= 1) { s += __shfl_xor(s, d); q += __shfl_xor(q, d); }
  const float mu = s * (1.0f / DIM);
  const float rs = rsqrtf(q * (1.0f / DIM) - mu * mu + 1e-5f);
  const int j = row % NJ;
  const float* gp = lg + j * DIM + lane * 8;
  const float* bp = lb + j * DIM + lane * 8;
  float g[8], b[8];
  *(float4*)(g)     = *(const float4*)(gp);
  *(float4*)(g + 4) = *(const float4*)(gp + 4);
  *(float4*)(b)     = *(const float4*)(bp);
  *(float4*)(b + 4) = *(const float4*)(bp + 4);
  union { bf16x8 v8; __hip_bfloat16 h[8]; } u;
#pragma unroll
  for (int i = 0; i < 8; ++i) u.h[i] = __float2bfloat16((v[i] - mu) * rs * g[i] + b[i]);
  *(bf16x8*)(xn + (size_t)row * DIM + lane * 8) = u.v8;
}

// ---------------- w1 [J][D][M] f32 -> w1t [J][M][D] bf16 ----------------
__global__ void k_w1t(const float* __restrict__ w1, __hip_bfloat16* __restrict__ w1t) {
  __shared__ float t[64][65];
  const int j = blockIdx.z;
  const int k0 = blockIdx.x * 64;
  const int n0 = blockIdx.y * 64;
  const int tid = threadIdx.x;
  const int rr = tid >> 4;         // 0..15
  const int cc = (tid & 15) * 4;   // 0..60
  const float* src = w1 + ((size_t)j * DIM + k0) * MLP + n0;
#pragma unroll
  for (int i = 0; i < 4; ++i) {
    const int k = rr + i * 16;
    float4 vv = *(const float4*)(src + (size_t)k * MLP + cc);
    t[k][cc + 0] = vv.x; t[k][cc + 1] = vv.y; t[k][cc + 2] = vv.z; t[k][cc + 3] = vv.w;
  }
  __syncthreads();
  __hip_bfloat16* dst = w1t + ((size_t)j * MLP + n0) * DIM + k0;
#pragma unroll
  for (int i = 0; i < 4; ++i) {
    const int n = rr + i * 16;
    union { ushort4 u4; __hip_bfloat16 h[4]; } pk;
    pk.h[0] = __float2bfloat16(t[cc + 0][n]);
    pk.h[1] = __float2bfloat16(t[cc + 1][n]);
    pk.h[2] = __float2bfloat16(t[cc + 2][n]);
    pk.h[3] = __float2bfloat16(t[cc + 3][n]);
    *(ushort4*)(dst + (size_t)n * DIM + cc) = pk.u4;
  }
}

// ---------------- y init with b2 ----------------
__global__ void k_yinit(const float* __restrict__ b2, float* __restrict__ y, int total) {
  const int i = blockIdx.x * 256 + threadIdx.x;
  if (i < total) {
    const int o = i % 3;
    const int j = (i / 3) % NJ;
    y[i] = b2[j * 3 + o];
  }
}

// ---------------- fused grouped GEMM: xn @ w1 -> gelu -> @ w2 -> atomicAdd y ----
// grid (B/128, MLP/128, NJ), block 256 (4 waves, 2x2), wave tile 64x64
__launch_bounds__(256)
__global__ void k_gemm(const __hip_bfloat16* __restrict__ xn,
                       const __hip_bfloat16* __restrict__ w1t,
                       const float* __restrict__ b1,
                       const float* __restrict__ w2,
                       float* __restrict__ y) {
  __shared__ __hip_bfloat16 As[128 * 64];
  __shared__ __hip_bfloat16 Bs[128 * 64];
  const int mt = blockIdx.x, nt = blockIdx.y, j = blockIdx.z;
  const int tid = threadIdx.x;
  const int wid = tid >> 6, lane = tid & 63;
  const int wr = wid >> 1, wc = wid & 1;
  const int b0 = mt * 128, n0 = nt * 128;

  f32x4 acc[4][4];
#pragma unroll
  for (int m = 0; m < 4; ++m)
#pragma unroll
    for (int n = 0; n < 4; ++n)
#pragma unroll
      for (int r = 0; r < 4; ++r) acc[m][n][r] = 0.0f;

  const int rsub = lane >> 3;          // 0..7 row within 8-row chunk
  const int csub = (lane & 7) * 8;     // bf16 element offset within 64-wide row

  for (int kk = 0; kk < 8; ++kk) {
#pragma unroll
    for (int i = 0; i < 4; ++i) {
      const int ch = wid * 4 + i;             // 0..15 (8 rows each)
      const int row = ch * 8 + rsub;          // 0..127
      const __hip_bfloat16* ga =
          xn + ((size_t)(b0 + row) * NJ + j) * DIM + kk * 64 + csub;
      gload_lds16(ga, (void*)((char*)As + ch * 1024));
      const __hip_bfloat16* gb =
          w1t + ((size_t)j * MLP + n0 + row) * DIM + kk * 64 + csub;
      gload_lds16(gb, (void*)((char*)Bs + ch * 1024));
    }
    asm volatile("s_waitcnt vmcnt(0)" ::: "memory");
    __syncthreads();

#pragma unroll
    for (int s = 0; s < 2; ++s) {
      bf16x8 af[4], bfr[4];
#pragma unroll
      for (int m = 0; m < 4; ++m) {
        const int row = wr * 64 + m * 16 + (lane & 15);
        af[m] = *(const bf16x8*)&As[row * 64 + s * 32 + (lane >> 4) * 8];
      }
#pragma unroll
      for (int n = 0; n < 4; ++n) {
        const int row = wc * 64 + n * 16 + (lane & 15);
        bfr[n] = *(const bf16x8*)&Bs[row * 64 + s * 32 + (lane >> 4) * 8];
      }
#pragma unroll
      for (int m = 0; m < 4; ++m)
#pragma unroll
        for (int n = 0; n < 4; ++n)
          acc[m][n] = __builtin_amdgcn_mfma_f32_16x16x32_bf16(af[m], bfr[n], acc[m][n], 0, 0, 0);
    }
    __syncthreads();
  }

  // epilogue: bias + exact GELU + contract vs w2 into per-lane partials
  const int cl = lane & 15, gq = lane >> 4;
  float p[4][4][3];
#pragma unroll
  for (int m = 0; m < 4; ++m)
#pragma unroll
    for (int r = 0; r < 4; ++r)
#pragma unroll
      for (int o = 0; o < 3; ++o) p[m][r][o] = 0.0f;

#pragma unroll
  for (int nn = 0; nn < 4; ++nn) {
    const int n = n0 + wc * 64 + nn * 16 + cl;
    const float bias = b1[j * MLP + n];
    const size_t w2o = ((size_t)j * MLP + n) * 3;
    const float w20 = w2[w2o + 0], w21 = w2[w2o + 1], w22 = w2[w2o + 2];
#pragma unroll
    for (int m = 0; m < 4; ++m)
#pragma unroll
      for (int r = 0; r < 4; ++r) {
        const float h = acc[m][nn][r] + bias;
        const float ge = 0.5f * h * (1.0f + erff(h * 0.70710678118654752f));
        p[m][r][0] += ge * w20;
        p[m][r][1] += ge * w21;
        p[m][r][2] += ge * w22;
      }
  }

  // reduce over the 16 column lanes, then atomic-accumulate
#pragma unroll
  for (int m = 0; m < 4; ++m)
#pragma unroll
    for (int r = 0; r < 4; ++r)
#pragma unroll
      for (int o = 0; o < 3; ++o) {
        float v = p[m][r][o];
        v += __shfl_xor(v, 1);
        v += __shfl_xor(v, 2);
        v += __shfl_xor(v, 4);
        v += __shfl_xor(v, 8);
        if (cl == 0) {
          const int brow = b0 + wr * 64 + m * 16 + gq * 4 + r;
          atomicAdd(&y[((size_t)brow * NJ + j) * 3 + o], v);
        }
      }
}

extern "C" void kernel_launch(void* const* d_in, const int* in_sizes, int n_in,
                              void* d_out, int out_size, void* d_ws, size_t ws_size,
                              hipStream_t stream) {
  const float* x  = (const float*)d_in[0];
  const float* lg = (const float*)d_in[1];
  const float* lb = (const float*)d_in[2];
  const float* w1 = (const float*)d_in[3];
  const float* b1 = (const float*)d_in[4];
  const float* w2 = (const float*)d_in[5];
  const float* b2 = (const float*)d_in[6];
  float* y = (float*)d_out;

  const int B = in_sizes[0] / (NJ * DIM);   // 4096

  __hip_bfloat16* xnp  = (__hip_bfloat16*)d_ws;
  __hip_bfloat16* w1tp = (__hip_bfloat16*)((char*)d_ws + (size_t)B * NJ * DIM * 2);

  k_ln<<<dim3((B * NJ) / 4), 256, 0, stream>>>(x, lg, lb, xnp, B * NJ);
  k_w1t<<<dim3(DIM / 64, MLP / 64, NJ), 256, 0, stream>>>(w1, w1tp);
  k_yinit<<<dim3((B * NJ * 3 + 255) / 256), 256, 0, stream>>>(b2, y, B * NJ * 3);
  k_gemm<<<dim3(B / 128, MLP / 128, NJ), 256, 0, stream>>>(xnp, w1tp, b1, w2, y);
}

// Round 8
// 897.971 us; speedup vs baseline: 1.7933x; 1.7933x over previous
//
#include <hip/hip_runtime.h>
#include <hip/hip_bf16.h>
#include <stdint.h>

#define DIM 512
#define MLP 2048
#define NJ  24

typedef __attribute__((ext_vector_type(8))) short bf16x8;
typedef __attribute__((ext_vector_type(4))) float f32x4;

__device__ __forceinline__ void gload_lds16(const void* g, void* l) {
  __builtin_amdgcn_global_load_lds(
      (const __attribute__((address_space(1))) uint8_t*)g,
      (__attribute__((address_space(3))) uint8_t*)l, 16, 0, 0);
}

// ---------------- LayerNorm -> bf16, swizzled+tiled xsw[j][mt][kk][128][64] ----
// one wave per (b,j) row; block=256 -> 4 rows/block
__global__ void k_ln(const float* __restrict__ x, const float* __restrict__ lg,
                     const float* __restrict__ lb, char* __restrict__ xsw,
                     int nrows) {
  const int rowg = blockIdx.x * 4 + (threadIdx.x >> 6);
  const int lane = threadIdx.x & 63;
  if (rowg >= nrows) return;
  const int b = rowg / NJ;
  const int j = rowg - b * NJ;
  const float* xr = x + (size_t)rowg * DIM + lane * 8;
  float v[8];
  *(float4*)(v)     = *(const float4*)(xr);
  *(float4*)(v + 4) = *(const float4*)(xr + 4);
  float s = 0.f, q = 0.f;
#pragma unroll
  for (int i = 0; i < 8; ++i) { s += v[i]; q += v[i] * v[i]; }
#pragma unroll
  for (int d = 1; d < 64; d <<= 1) { s += __shfl_xor(s, d); q += __shfl_xor(q, d); }
  const float mu = s * (1.0f / DIM);
  const float rs = rsqrtf(q * (1.0f / DIM) - mu * mu + 1e-5f);
  const float* gp = lg + j * DIM + lane * 8;
  const float* bp = lb + j * DIM + lane * 8;
  float g[8], bb[8];
  *(float4*)(g)      = *(const float4*)(gp);
  *(float4*)(g + 4)  = *(const float4*)(gp + 4);
  *(float4*)(bb)     = *(const float4*)(bp);
  *(float4*)(bb + 4) = *(const float4*)(bp + 4);
  union { bf16x8 v8; __hip_bfloat16 h[8]; } u;
#pragma unroll
  for (int i = 0; i < 8; ++i) u.h[i] = __float2bfloat16((v[i] - mu) * rs * g[i] + bb[i]);
  // swizzled dest: chunk kk = lane>>3, colb = ((lane&7)*16) ^ ((r&7)<<4)
  const int mt = b >> 7, r = b & 127;
  const int kk = lane >> 3;
  const int colb = ((lane & 7) * 16) ^ ((r & 7) << 4);
  char* dst = xsw + (((size_t)j * 32 + mt) * 8 + kk) * 16384 + r * 128 + colb;
  *(bf16x8*)dst = u.v8;
}

// ---------------- w1 [J][D][M] f32 -> wsw[j][nt][kk][128 n][64 k] bf16 swizzled ----
// grid (nt=16, j=24), block 256
__global__ void k_w1t(const float* __restrict__ w1, char* __restrict__ wsw) {
  __shared__ float t32[64][132];
  const int nt = blockIdx.x, j = blockIdx.y;
  const int t = threadIdx.x;
  for (int kk = 0; kk < 8; ++kk) {
    // phase 1: coalesced load of [64 k][128 n] f32 tile
#pragma unroll
    for (int i = 0; i < 8; ++i) {
      const int A = t * 16 + i * 4096;         // byte offset in 32KB tile
      const int k = A >> 9;                     // 0..63
      const int n4 = (A & 511) >> 2;            // 0..124 step 4
      const float4 vv = *(const float4*)(w1 +
          ((size_t)j * DIM + kk * 64 + k) * MLP + nt * 128 + n4);
      t32[k][n4 + 0] = vv.x; t32[k][n4 + 1] = vv.y;
      t32[k][n4 + 2] = vv.z; t32[k][n4 + 3] = vv.w;
    }
    __syncthreads();
    // phase 2: transposed, swizzled bf16 write (16KB out per kk)
#pragma unroll
    for (int i2 = 0; i2 < 4; ++i2) {
      const int D = i2 * 4096 + t * 16;
      const int row = D >> 7;                   // n_local 0..127
      const int colbp = D & 127;
      const int colb = colbp ^ ((row & 7) << 4);
      const int e0 = colb >> 1;                 // k_local, 8 consecutive
      union { bf16x8 v8; __hip_bfloat16 h[8]; } u;
#pragma unroll
      for (int e = 0; e < 8; ++e) u.h[e] = __float2bfloat16(t32[e0 + e][row]);
      *(bf16x8*)(wsw + ((size_t)j * 16 + nt) * 131072 + kk * 16384 + D) = u.v8;
    }
    __syncthreads();
  }
}

// ---------------- fused grouped GEMM ----------------
// grid (mt=32, j=24), block 256 (4 waves, each 32 rows x 128 cols)
__launch_bounds__(256)
__global__ void k_gemm(const char* __restrict__ xsw, const char* __restrict__ wsw,
                       const float* __restrict__ b1, const float* __restrict__ w2,
                       const float* __restrict__ b2, float* __restrict__ y) {
  __shared__ __align__(16) char smem[163840];
  char* As = smem;            // [8][128][64] bf16 swizzled, 128KB
  char* Bs = smem + 131072;   // [2][128][64] bf16 swizzled, 32KB
  const int mt = blockIdx.x, j = blockIdx.y;
  const int tid = threadIdx.x, wid = tid >> 6, lane = tid & 63;
  const int cl = lane & 15, gq = lane >> 4;
  const int swz = (cl & 7) << 4;

  const char* abase = xsw + ((size_t)j * 32 + mt) * 131072;
  const char* wbase = wsw + (size_t)j * 2097152;

  // stage full A stripe (128KB), contiguous
  {
    const char* gaw = abase + wid * 1024 + lane * 16;
    char* law = As + wid * 1024;
#pragma unroll
    for (int i = 0; i < 32; ++i)
      gload_lds16(gaw + i * 4096, law + i * 4096);
  }
  // stage B(nt=0,kk=0) into buf 0
  {
    const char* g = wbase + wid * 1024 + lane * 16;
    char* l = Bs + wid * 1024;
#pragma unroll
    for (int i = 0; i < 4; ++i) gload_lds16(g + i * 4096, l + i * 4096);
  }
  asm volatile("s_waitcnt vmcnt(0)" ::: "memory");
  __syncthreads();

  float p[2][4][3];
#pragma unroll
  for (int m = 0; m < 2; ++m)
#pragma unroll
    for (int r = 0; r < 4; ++r)
#pragma unroll
      for (int o = 0; o < 3; ++o) p[m][r][o] = 0.0f;

  int buf = 0;
  for (int nt = 0; nt < 16; ++nt) {
    f32x4 acc[2][8];
#pragma unroll
    for (int m = 0; m < 2; ++m)
#pragma unroll
      for (int n = 0; n < 8; ++n)
#pragma unroll
        for (int r = 0; r < 4; ++r) acc[m][n][r] = 0.0f;

#pragma unroll
    for (int kk = 0; kk < 8; ++kk) {
      // stage next B tile into buf^1
      const int tstep = nt * 8 + kk;
      if (tstep + 1 < 128) {
        const int nn = tstep + 1;
        const char* g = wbase + ((size_t)nn << 14) + wid * 1024 + lane * 16;
        char* l = Bs + (buf ^ 1) * 16384 + wid * 1024;
#pragma unroll
        for (int i = 0; i < 4; ++i) gload_lds16(g + i * 4096, l + i * 4096);
      }
      // compute on As[kk], Bs[buf]
      const char* Ab = As + kk * 16384;
      const char* Bb = Bs + buf * 16384;
#pragma unroll
      for (int s = 0; s < 2; ++s) {
        const int cbS = (s * 64 + gq * 16) ^ swz;
        bf16x8 af[2], bfr[8];
#pragma unroll
        for (int m = 0; m < 2; ++m)
          af[m] = *(const bf16x8*)(Ab + (wid * 32 + m * 16 + cl) * 128 + cbS);
#pragma unroll
        for (int n = 0; n < 8; ++n)
          bfr[n] = *(const bf16x8*)(Bb + (n * 16 + cl) * 128 + cbS);
#pragma unroll
        for (int m = 0; m < 2; ++m)
#pragma unroll
          for (int n = 0; n < 8; ++n)
            acc[m][n] = __builtin_amdgcn_mfma_f32_16x16x32_bf16(af[m], bfr[n], acc[m][n], 0, 0, 0);
      }
      asm volatile("s_waitcnt vmcnt(0)" ::: "memory");
      __syncthreads();
      buf ^= 1;
    }

    // per-nt epilogue: bias + exact GELU + contract vs w2 into p
#pragma unroll
    for (int n = 0; n < 8; ++n) {
      const int col = nt * 128 + n * 16 + cl;
      const float bias = b1[j * MLP + col];
      const float* w2p = w2 + ((size_t)j * MLP + col) * 3;
      const float w20 = w2p[0], w21 = w2p[1], w22 = w2p[2];
#pragma unroll
      for (int m = 0; m < 2; ++m)
#pragma unroll
        for (int r = 0; r < 4; ++r) {
          const float h = acc[m][n][r] + bias;
          const float ge = 0.5f * h * (1.0f + erff(h * 0.70710678118654752f));
          p[m][r][0] += ge * w20;
          p[m][r][1] += ge * w21;
          p[m][r][2] += ge * w22;
        }
    }
  }

  // final reduce over the 16 column lanes (cl) and store y (+b2)
  const int b0 = mt * 128;
#pragma unroll
  for (int m = 0; m < 2; ++m)
#pragma unroll
    for (int r = 0; r < 4; ++r)
#pragma unroll
      for (int o = 0; o < 3; ++o) {
        float v = p[m][r][o];
        v += __shfl_xor(v, 1);
        v += __shfl_xor(v, 2);
        v += __shfl_xor(v, 4);
        v += __shfl_xor(v, 8);
        if (cl == 0) {
          const int brow = b0 + wid * 32 + m * 16 + gq * 4 + r;
          y[(size_t)brow * NJ * 3 + j * 3 + o] = v + b2[j * 3 + o];
        }
      }
}

extern "C" void kernel_launch(void* const* d_in, const int* in_sizes, int n_in,
                              void* d_out, int out_size, void* d_ws, size_t ws_size,
                              hipStream_t stream) {
  const float* x  = (const float*)d_in[0];
  const float* lg = (const float*)d_in[1];
  const float* lb = (const float*)d_in[2];
  const float* w1 = (const float*)d_in[3];
  const float* b1 = (const float*)d_in[4];
  const float* w2 = (const float*)d_in[5];
  const float* b2 = (const float*)d_in[6];
  float* y = (float*)d_out;

  const int B = in_sizes[0] / (NJ * DIM);   // 4096

  char* xswp = (char*)d_ws;                                   // [J][B/128][8][128][64] bf16
  char* wswp = (char*)d_ws + (size_t)NJ * (B / 128) * 131072; // [J][16][8][128][64] bf16

  k_ln<<<dim3((B * NJ) / 4), 256, 0, stream>>>(x, lg, lb, xswp, B * NJ);
  k_w1t<<<dim3(16, NJ), 256, 0, stream>>>(w1, wswp);
  k_gemm<<<dim3(B / 128, NJ), 256, 0, stream>>>(xswp, wswp, b1, w2, b2, y);
}